// Round 1
// baseline (1060.465 us; speedup 1.0000x reference)
//
#include <hip/hip_runtime.h>

typedef unsigned short u16;
typedef __attribute__((ext_vector_type(8))) short short8;
typedef __attribute__((ext_vector_type(4))) float f32x4;

#define L 4096
#define DMODEL 2048
#define NHEADS 16
#define DHEAD 128

__device__ __forceinline__ u16 f2bf(float f){
  union { float f; unsigned int i; } v; v.f = f;
  unsigned int u = v.i;
  u += 0x7fffu + ((u >> 16) & 1u);
  return (u16)(u >> 16);
}

__global__ void cast_kernel(const float* __restrict__ in, u16* __restrict__ out, int n){
  int stride = gridDim.x * blockDim.x * 4;
  for (int j = (blockIdx.x * blockDim.x + threadIdx.x) * 4; j < n; j += stride){
    float4 f = *reinterpret_cast<const float4*>(in + j);
    ushort4 o;
    o.x = f2bf(f.x); o.y = f2bf(f.y); o.z = f2bf(f.z); o.w = f2bf(f.w);
    *reinterpret_cast<ushort4*>(out + j) = o;
  }
}

__device__ __forceinline__ void gl_lds16(void* lds, const void* g){
  __builtin_amdgcn_global_load_lds(
      (const __attribute__((address_space(1))) unsigned int*)g,
      (__attribute__((address_space(3))) unsigned int*)lds, 16, 0, 0);
}

// C = A @ B^T (+bias). A: [4096][2048] bf16 row-major, B: [2048][2048] bf16 row-major.
// MODE 0: write bf16 out[H][L][128] at (h=col>>7, l=row, dh=col&127)   (Q, K)
// MODE 1: write bf16 out[H][128][L] at (h=col>>7, dh=col&127, l=row)   (V transposed)
// MODE 2: write f32  out[row*2048 + col]                               (final output)
template<int MODE>
__global__ __launch_bounds__(256) void gemm_bt(const u16* __restrict__ A, const u16* __restrict__ Bw,
                                               const float* __restrict__ bias, void* __restrict__ outp){
  __shared__ u16 As[128*32];
  __shared__ u16 Bs[128*32];
  const int tid = threadIdx.x;
  const int wid = tid >> 6, lane = tid & 63;
  const int wr = wid >> 1, wc = wid & 1;
  const int g = lane >> 4, r = lane & 15;

  const u16* Ag = A + ((size_t)(blockIdx.x * 128 + wid * 32 + (lane >> 2))) * DMODEL + (lane & 3) * 8;
  const u16* Bg = Bw + ((size_t)(blockIdx.y * 128 + wid * 32 + (lane >> 2))) * DMODEL + (lane & 3) * 8;
  u16* AsW = As + wid * 1024;
  u16* BsW = Bs + wid * 1024;

  f32x4 acc[4][4];
  #pragma unroll
  for (int m = 0; m < 4; ++m)
    #pragma unroll
    for (int n = 0; n < 4; ++n) acc[m][n] = (f32x4){0.f, 0.f, 0.f, 0.f};

  for (int k0 = 0; k0 < DMODEL; k0 += 32){
    __syncthreads();
    gl_lds16(AsW,       Ag + k0);
    gl_lds16(AsW + 512, Ag + k0 + 16 * DMODEL);
    gl_lds16(BsW,       Bg + k0);
    gl_lds16(BsW + 512, Bg + k0 + 16 * DMODEL);
    __syncthreads();

    short8 a[4], b[4];
    #pragma unroll
    for (int m = 0; m < 4; ++m)
      a[m] = *reinterpret_cast<const short8*>(&As[(wr * 64 + m * 16 + r) * 32 + g * 8]);
    #pragma unroll
    for (int n = 0; n < 4; ++n)
      b[n] = *reinterpret_cast<const short8*>(&Bs[(wc * 64 + n * 16 + r) * 32 + g * 8]);
    #pragma unroll
    for (int m = 0; m < 4; ++m)
      #pragma unroll
      for (int n = 0; n < 4; ++n)
        acc[m][n] = __builtin_amdgcn_mfma_f32_16x16x32_bf16(a[m], b[n], acc[m][n], 0, 0, 0);
  }

  const int ibase = blockIdx.x * 128 + wr * 64;
  const int jbase = blockIdx.y * 128 + wc * 64;
  #pragma unroll
  for (int n = 0; n < 4; ++n){
    int col = jbase + n * 16 + r;
    float bv = bias[col];
    #pragma unroll
    for (int m = 0; m < 4; ++m){
      #pragma unroll
      for (int q = 0; q < 4; ++q){
        int row = ibase + m * 16 + g * 4 + q;
        float c = acc[m][n][q] + bv;
        if (MODE == 0){
          ((u16*)outp)[(size_t)(col >> 7) * (L * DHEAD) + (size_t)row * DHEAD + (col & 127)] = f2bf(c);
        } else if (MODE == 1){
          ((u16*)outp)[(size_t)(col >> 7) * (DHEAD * L) + (size_t)(col & 127) * L + row] = f2bf(c);
        } else {
          ((float*)outp)[(size_t)row * DMODEL + col] = c;
        }
      }
    }
  }
}

// Flash attention. Q,K: [H][L][128] bf16. Vt: [H][128][L] bf16. Ob: [L][2048] bf16.
// One wave handles 16 q-rows. 4 independent waves per block.
__global__ __launch_bounds__(256) void attn_kernel(const u16* __restrict__ Q, const u16* __restrict__ Km,
                                                   const u16* __restrict__ Vt, u16* __restrict__ Ob,
                                                   const int* __restrict__ is_causal_p){
  __shared__ u16 plds[4][16 * 72];   // P staging, stride 72 breaks bank conflicts
  const int lane = threadIdx.x & 63, wid = threadIdx.x >> 6;
  const int g = lane >> 4, r = lane & 15;
  const int head = blockIdx.x >> 6;
  const int q0 = (blockIdx.x & 63) * 64 + wid * 16;
  const int causal = *is_causal_p;

  const u16* Qh = Q  + (size_t)head * L * DHEAD;
  const u16* Kh = Km + (size_t)head * L * DHEAD;
  const u16* Vh = Vt + (size_t)head * DHEAD * L;
  u16* P = plds[wid];

  short8 qf[4];
  #pragma unroll
  for (int kb = 0; kb < 4; ++kb)
    qf[kb] = *reinterpret_cast<const short8*>(&Qh[(size_t)(q0 + r) * DHEAD + kb * 32 + g * 8]);

  f32x4 o[8];
  #pragma unroll
  for (int db = 0; db < 8; ++db) o[db] = (f32x4){0.f, 0.f, 0.f, 0.f};
  float mrow[4] = {-1e30f, -1e30f, -1e30f, -1e30f};
  float lrow[4] = {0.f, 0.f, 0.f, 0.f};

  const int kvend = causal ? (q0 + 16) : L;
  const float scale = 0.08838834764831845f;  // 1/sqrt(128)

  for (int kv0 = 0; kv0 < kvend; kv0 += 64){
    // ---- S = Q K^T for a 16x64 tile (NT-safe fragment loads) ----
    f32x4 s[4];
    #pragma unroll
    for (int cb = 0; cb < 4; ++cb){
      s[cb] = (f32x4){0.f, 0.f, 0.f, 0.f};
      #pragma unroll
      for (int kb = 0; kb < 4; ++kb){
        short8 kf = *reinterpret_cast<const short8*>(&Kh[(size_t)(kv0 + cb * 16 + r) * DHEAD + kb * 32 + g * 8]);
        s[cb] = __builtin_amdgcn_mfma_f32_16x16x32_bf16(qf[kb], kf, s[cb], 0, 0, 0);
      }
    }
    // ---- scale + causal mask + row max ----
    float pmax[4] = {-1e30f, -1e30f, -1e30f, -1e30f};
    #pragma unroll
    for (int cb = 0; cb < 4; ++cb){
      int kvcol = kv0 + cb * 16 + r;
      #pragma unroll
      for (int q = 0; q < 4; ++q){
        float v = s[cb][q] * scale;
        int qrow = q0 + g * 4 + q;
        if (causal && kvcol > qrow) v = -1e30f;
        s[cb][q] = v;
        pmax[q] = fmaxf(pmax[q], v);
      }
    }
    #pragma unroll
    for (int q = 0; q < 4; ++q){
      #pragma unroll
      for (int off = 1; off < 16; off <<= 1)
        pmax[q] = fmaxf(pmax[q], __shfl_xor(pmax[q], off));
    }
    // ---- online softmax update ----
    float alpha[4], rsum[4];
    #pragma unroll
    for (int q = 0; q < 4; ++q){
      float mn = fmaxf(mrow[q], pmax[q]);
      alpha[q] = __expf(mrow[q] - mn);
      mrow[q] = mn;
      rsum[q] = 0.f;
    }
    #pragma unroll
    for (int cb = 0; cb < 4; ++cb)
      #pragma unroll
      for (int q = 0; q < 4; ++q){
        float p = __expf(s[cb][q] - mrow[q]);
        s[cb][q] = p;
        rsum[q] += p;
      }
    #pragma unroll
    for (int q = 0; q < 4; ++q){
      #pragma unroll
      for (int off = 1; off < 16; off <<= 1)
        rsum[q] += __shfl_xor(rsum[q], off);
      lrow[q] = lrow[q] * alpha[q] + rsum[q];
    }
    #pragma unroll
    for (int db = 0; db < 8; ++db)
      #pragma unroll
      for (int q = 0; q < 4; ++q)
        o[db][q] *= alpha[q];
    // ---- P (C-layout) -> LDS -> A-fragments ----
    #pragma unroll
    for (int cb = 0; cb < 4; ++cb)
      #pragma unroll
      for (int q = 0; q < 4; ++q)
        P[(g * 4 + q) * 72 + cb * 16 + r] = f2bf(s[cb][q]);
    asm volatile("s_waitcnt lgkmcnt(0)" ::: "memory");
    // ---- O += P @ V (V read from transposed layout, NT-safe) ----
    #pragma unroll
    for (int st = 0; st < 2; ++st){
      short8 pa = *reinterpret_cast<const short8*>(&P[r * 72 + st * 32 + g * 8]);
      #pragma unroll
      for (int db = 0; db < 8; ++db){
        short8 vf = *reinterpret_cast<const short8*>(&Vh[(size_t)(db * 16 + r) * L + kv0 + st * 32 + g * 8]);
        o[db] = __builtin_amdgcn_mfma_f32_16x16x32_bf16(pa, vf, o[db], 0, 0, 0);
      }
    }
  }
  // ---- epilogue: O / l, write [L][2048] bf16 ----
  #pragma unroll
  for (int db = 0; db < 8; ++db){
    #pragma unroll
    for (int q = 0; q < 4; ++q){
      float val = o[db][q] / lrow[q];
      int qrow = q0 + g * 4 + q;
      Ob[(size_t)qrow * DMODEL + head * DHEAD + db * 16 + r] = f2bf(val);
    }
  }
}

extern "C" void kernel_launch(void* const* d_in, const int* in_sizes, int n_in,
                              void* d_out, int out_size, void* d_ws, size_t ws_size,
                              hipStream_t stream){
  const float* X  = (const float*)d_in[0];
  const float* Wq = (const float*)d_in[1];
  const float* bq = (const float*)d_in[2];
  const float* Wk = (const float*)d_in[3];
  const float* bk = (const float*)d_in[4];
  const float* Wv = (const float*)d_in[5];
  const float* bv = (const float*)d_in[6];
  const float* Wo = (const float*)d_in[7];
  const float* bo = (const float*)d_in[8];
  const int*   isc = (const int*)d_in[9];

  char* ws = (char*)d_ws;
  u16* Xb  = (u16*)(ws);              // 16 MiB, reused as Ob after V-GEMM
  u16* Qb  = (u16*)(ws + 16777216);
  u16* Kb  = (u16*)(ws + 33554432);
  u16* Vtb = (u16*)(ws + 50331648);
  u16* Wqb = (u16*)(ws + 67108864);
  u16* Wkb = (u16*)(ws + 75497472);
  u16* Wvb = (u16*)(ws + 83886080);
  u16* Wob = (u16*)(ws + 92274688);
  u16* Ob  = Xb;

  cast_kernel<<<2048, 256, 0, stream>>>(X,  Xb,  L * DMODEL);
  cast_kernel<<<1024, 256, 0, stream>>>(Wq, Wqb, DMODEL * DMODEL);
  cast_kernel<<<1024, 256, 0, stream>>>(Wk, Wkb, DMODEL * DMODEL);
  cast_kernel<<<1024, 256, 0, stream>>>(Wv, Wvb, DMODEL * DMODEL);
  cast_kernel<<<1024, 256, 0, stream>>>(Wo, Wob, DMODEL * DMODEL);

  dim3 gg(32, 16);
  gemm_bt<0><<<gg, 256, 0, stream>>>(Xb, Wqb, bq, Qb);
  gemm_bt<0><<<gg, 256, 0, stream>>>(Xb, Wkb, bk, Kb);
  gemm_bt<1><<<gg, 256, 0, stream>>>(Xb, Wvb, bv, Vtb);

  attn_kernel<<<NHEADS * (L / 64), 256, 0, stream>>>(Qb, Kb, Vtb, Ob, isc);

  gemm_bt<2><<<gg, 256, 0, stream>>>(Ob, Wob, bo, d_out);
}

// Round 2
// 617.336 us; speedup vs baseline: 1.7178x; 1.7178x over previous
//
#include <hip/hip_runtime.h>

typedef unsigned short u16;
typedef __attribute__((ext_vector_type(8))) short short8;
typedef __attribute__((ext_vector_type(4))) float f32x4;

#define L 4096
#define DMODEL 2048
#define NHEADS 16
#define DHEAD 128

__device__ __forceinline__ u16 f2bf(float f){
  union { float f; unsigned int i; } v; v.f = f;
  unsigned int u = v.i;
  u += 0x7fffu + ((u >> 16) & 1u);
  return (u16)(u >> 16);
}

__global__ void cast_kernel(const float* __restrict__ in, u16* __restrict__ out, int n){
  int stride = gridDim.x * blockDim.x * 4;
  for (int j = (blockIdx.x * blockDim.x + threadIdx.x) * 4; j < n; j += stride){
    float4 f = *reinterpret_cast<const float4*>(in + j);
    ushort4 o;
    o.x = f2bf(f.x); o.y = f2bf(f.y); o.z = f2bf(f.z); o.w = f2bf(f.w);
    *reinterpret_cast<ushort4*>(out + j) = o;
  }
}

__device__ __forceinline__ void gl_lds16(void* lds, const void* g){
  __builtin_amdgcn_global_load_lds(
      (const __attribute__((address_space(1))) unsigned int*)g,
      (__attribute__((address_space(3))) unsigned int*)lds, 16, 0, 0);
}

// C = A @ B^T (+bias). A: [4096][2048] bf16 row-major, B: [2048][2048] bf16 row-major.
// MODE 0: write bf16 out[H][L][128] at (h=col>>7, l=row, dh=col&127)   (Q, K)
// MODE 1: write bf16 out[H][128][L] at (h=col>>7, dh=col&127, l=row)   (V transposed)
// MODE 2: write f32  out[row*2048 + col]                               (final output)
template<int MODE>
__global__ __launch_bounds__(256) void gemm_bt(const u16* __restrict__ A, const u16* __restrict__ Bw,
                                               const float* __restrict__ bias, void* __restrict__ outp){
  __shared__ u16 As[128*32];
  __shared__ u16 Bs[128*32];
  const int tid = threadIdx.x;
  const int wid = tid >> 6, lane = tid & 63;
  const int wr = wid >> 1, wc = wid & 1;
  const int g = lane >> 4, r = lane & 15;

  const u16* Ag = A + ((size_t)(blockIdx.x * 128 + wid * 32 + (lane >> 2))) * DMODEL + (lane & 3) * 8;
  const u16* Bg = Bw + ((size_t)(blockIdx.y * 128 + wid * 32 + (lane >> 2))) * DMODEL + (lane & 3) * 8;
  u16* AsW = As + wid * 1024;
  u16* BsW = Bs + wid * 1024;

  f32x4 acc[4][4];
  #pragma unroll
  for (int m = 0; m < 4; ++m)
    #pragma unroll
    for (int n = 0; n < 4; ++n) acc[m][n] = (f32x4){0.f, 0.f, 0.f, 0.f};

  for (int k0 = 0; k0 < DMODEL; k0 += 32){
    __syncthreads();
    gl_lds16(AsW,       Ag + k0);
    gl_lds16(AsW + 512, Ag + k0 + 16 * DMODEL);
    gl_lds16(BsW,       Bg + k0);
    gl_lds16(BsW + 512, Bg + k0 + 16 * DMODEL);
    __syncthreads();

    short8 a[4], b[4];
    #pragma unroll
    for (int m = 0; m < 4; ++m)
      a[m] = *reinterpret_cast<const short8*>(&As[(wr * 64 + m * 16 + r) * 32 + g * 8]);
    #pragma unroll
    for (int n = 0; n < 4; ++n)
      b[n] = *reinterpret_cast<const short8*>(&Bs[(wc * 64 + n * 16 + r) * 32 + g * 8]);
    #pragma unroll
    for (int m = 0; m < 4; ++m)
      #pragma unroll
      for (int n = 0; n < 4; ++n)
        acc[m][n] = __builtin_amdgcn_mfma_f32_16x16x32_bf16(a[m], b[n], acc[m][n], 0, 0, 0);
  }

  const int ibase = blockIdx.x * 128 + wr * 64;
  const int jbase = blockIdx.y * 128 + wc * 64;
  #pragma unroll
  for (int n = 0; n < 4; ++n){
    int col = jbase + n * 16 + r;
    float bv = bias[col];
    #pragma unroll
    for (int m = 0; m < 4; ++m){
      #pragma unroll
      for (int q = 0; q < 4; ++q){
        int row = ibase + m * 16 + g * 4 + q;
        float c = acc[m][n][q] + bv;
        if (MODE == 0){
          ((u16*)outp)[(size_t)(col >> 7) * (L * DHEAD) + (size_t)row * DHEAD + (col & 127)] = f2bf(c);
        } else if (MODE == 1){
          ((u16*)outp)[(size_t)(col >> 7) * (DHEAD * L) + (size_t)(col & 127) * L + row] = f2bf(c);
        } else {
          ((float*)outp)[(size_t)row * DMODEL + col] = c;
        }
      }
    }
  }
}

// Stage one 64x128 bf16 K tile into LDS (linear dest, XOR-swizzled global source).
// Tile = 16 KiB = 16 wave-instructions of 1 KiB; wave `wid` issues 4.
__device__ __forceinline__ void stage_K(u16* buf, const u16* Kh, int kv0, int wid, int lane){
  #pragma unroll
  for (int i = 0; i < 4; ++i){
    int ib = (wid * 4 + i) * 1024;
    int off = ib + lane * 16;
    int row = off >> 8;            // 256 B per row
    int c = off & 255;
    int sc = c ^ ((row & 7) << 4); // involutive swizzle
    gl_lds16((char*)buf + ib, (const char*)(Kh + (size_t)(kv0 + row) * DHEAD) + sc);
  }
}

// Flash attention. Q,K: [H][L][128] bf16. Vt: [H][128][L] bf16. Ob: [L][2048] bf16.
// Block = 4 waves, 128 q-rows (wave w: rows q0+w*16+{0..15} and q0+64+w*16+{0..15}).
// K double-buffered in LDS (swizzled), V read direct from transposed global layout.
__global__ __launch_bounds__(256, 2) void attn_kernel(const u16* __restrict__ Q, const u16* __restrict__ Km,
                                                      const u16* __restrict__ Vt, u16* __restrict__ Ob,
                                                      const int* __restrict__ is_causal_p){
  __shared__ u16 Ks[2][64 * 128];   // 32 KiB, double-buffered K tile
  __shared__ u16 Ps[4][32 * 72];    // 18 KiB, per-wave P staging (stride 72)
  const int lane = threadIdx.x & 63, wid = threadIdx.x >> 6;
  const int g = lane >> 4, r = lane & 15;

  // XCD-chunked + causal-balanced mapping: 512 blocks -> (head, qblk).
  int lg = (blockIdx.x & 7) * 64 + (blockIdx.x >> 3);
  int head = lg >> 5;
  int j = lg & 31;
  int qblk = (head & 1) ? (31 - j) : j;
  int q0 = qblk * 128;
  const int causal = *is_causal_p;

  const u16* Qh = Q  + (size_t)head * L * DHEAD;
  const u16* Kh = Km + (size_t)head * L * DHEAD;
  const u16* Vh = Vt + (size_t)head * DHEAD * L;
  u16* P = Ps[wid];

  // Q fragments: qf[m][kb], rows q0 + wid*16 + m*64 + r
  short8 qf[2][4];
  #pragma unroll
  for (int m = 0; m < 2; ++m)
    #pragma unroll
    for (int kb = 0; kb < 4; ++kb)
      qf[m][kb] = *reinterpret_cast<const short8*>(
          &Qh[(size_t)(q0 + wid * 16 + m * 64 + r) * DHEAD + kb * 32 + g * 8]);

  f32x4 o[2][8];
  #pragma unroll
  for (int m = 0; m < 2; ++m)
    #pragma unroll
    for (int db = 0; db < 8; ++db) o[m][db] = (f32x4){0.f, 0.f, 0.f, 0.f};
  float mrow[2][4], lrow[2][4];
  #pragma unroll
  for (int m = 0; m < 2; ++m)
    #pragma unroll
    for (int q = 0; q < 4; ++q){ mrow[m][q] = -1e30f; lrow[m][q] = 0.f; }

  const int nt = causal ? (2 * qblk + 2) : (L / 64);
  const float scale = 0.08838834764831845f;  // 1/sqrt(128)

  stage_K(Ks[0], Kh, 0, wid, lane);

  for (int t = 0; t < nt; ++t){
    const int kv0 = t * 64;
    if (t + 1 < nt){
      stage_K(Ks[(t + 1) & 1], Kh, kv0 + 64, wid, lane);
      asm volatile("s_waitcnt vmcnt(4)" ::: "memory");
    } else {
      asm volatile("s_waitcnt vmcnt(0)" ::: "memory");
    }
    __builtin_amdgcn_s_barrier();

    const bool active = (!causal) || (kv0 <= q0 + 79 + wid * 16);
    if (active){
      const char* Kb = (const char*)Ks[t & 1];
      // ---- S = Q K^T : 32 q-rows x 64 kv ----
      f32x4 s[2][4];
      #pragma unroll
      for (int m = 0; m < 2; ++m)
        #pragma unroll
        for (int cb = 0; cb < 4; ++cb) s[m][cb] = (f32x4){0.f, 0.f, 0.f, 0.f};
      #pragma unroll
      for (int cb = 0; cb < 4; ++cb){
        const int rr = cb * 16 + r;
        short8 kf[4];
        #pragma unroll
        for (int kb = 0; kb < 4; ++kb)
          kf[kb] = *reinterpret_cast<const short8*>(
              Kb + rr * 256 + ((kb * 64 + g * 16) ^ ((rr & 7) << 4)));
        #pragma unroll
        for (int m = 0; m < 2; ++m)
          #pragma unroll
          for (int kb = 0; kb < 4; ++kb)
            s[m][cb] = __builtin_amdgcn_mfma_f32_16x16x32_bf16(qf[m][kb], kf[kb], s[m][cb], 0, 0, 0);
      }
      // ---- scale + causal mask + online softmax ----
      #pragma unroll
      for (int m = 0; m < 2; ++m){
        float pmax[4] = {-1e30f, -1e30f, -1e30f, -1e30f};
        #pragma unroll
        for (int cb = 0; cb < 4; ++cb){
          int kvcol = kv0 + cb * 16 + r;
          #pragma unroll
          for (int q = 0; q < 4; ++q){
            float v = s[m][cb][q] * scale;
            int qrow = q0 + wid * 16 + m * 64 + g * 4 + q;
            if (causal && kvcol > qrow) v = -1e30f;
            s[m][cb][q] = v;
            pmax[q] = fmaxf(pmax[q], v);
          }
        }
        #pragma unroll
        for (int q = 0; q < 4; ++q){
          #pragma unroll
          for (int off = 1; off < 16; off <<= 1)
            pmax[q] = fmaxf(pmax[q], __shfl_xor(pmax[q], off));
        }
        float alpha[4], rsum[4];
        #pragma unroll
        for (int q = 0; q < 4; ++q){
          float mn = fmaxf(mrow[m][q], pmax[q]);
          alpha[q] = __expf(mrow[m][q] - mn);
          mrow[m][q] = mn;
          rsum[q] = 0.f;
        }
        #pragma unroll
        for (int cb = 0; cb < 4; ++cb)
          #pragma unroll
          for (int q = 0; q < 4; ++q){
            float p = __expf(s[m][cb][q] - mrow[m][q]);
            s[m][cb][q] = p;
            rsum[q] += p;
          }
        #pragma unroll
        for (int q = 0; q < 4; ++q){
          #pragma unroll
          for (int off = 1; off < 16; off <<= 1)
            rsum[q] += __shfl_xor(rsum[q], off);
          lrow[m][q] = lrow[m][q] * alpha[q] + rsum[q];
        }
        #pragma unroll
        for (int db = 0; db < 8; ++db)
          #pragma unroll
          for (int q = 0; q < 4; ++q)
            o[m][db][q] *= alpha[q];
        // P rows m*16 + g*4+q
        #pragma unroll
        for (int cb = 0; cb < 4; ++cb)
          #pragma unroll
          for (int q = 0; q < 4; ++q)
            P[(m * 16 + g * 4 + q) * 72 + cb * 16 + r] = f2bf(s[m][cb][q]);
      }
      asm volatile("s_waitcnt lgkmcnt(0)" ::: "memory");
      // ---- O += P @ V ----
      #pragma unroll
      for (int st = 0; st < 2; ++st){
        short8 pa[2];
        #pragma unroll
        for (int m = 0; m < 2; ++m)
          pa[m] = *reinterpret_cast<const short8*>(
              (const char*)P + (m * 16 + r) * 144 + st * 64 + g * 16);
        #pragma unroll
        for (int db = 0; db < 8; ++db){
          short8 vf = *reinterpret_cast<const short8*>(
              &Vh[(size_t)(db * 16 + r) * L + kv0 + st * 32 + g * 8]);
          #pragma unroll
          for (int m = 0; m < 2; ++m)
            o[m][db] = __builtin_amdgcn_mfma_f32_16x16x32_bf16(pa[m], vf, o[m][db], 0, 0, 0);
        }
      }
    }
    __builtin_amdgcn_s_barrier();
  }

  // ---- epilogue: O / l, write [L][2048] bf16 ----
  #pragma unroll
  for (int m = 0; m < 2; ++m)
    #pragma unroll
    for (int db = 0; db < 8; ++db)
      #pragma unroll
      for (int q = 0; q < 4; ++q){
        float val = o[m][db][q] / lrow[m][q];
        int qrow = q0 + wid * 16 + m * 64 + g * 4 + q;
        Ob[(size_t)qrow * DMODEL + head * DHEAD + db * 16 + r] = f2bf(val);
      }
}

extern "C" void kernel_launch(void* const* d_in, const int* in_sizes, int n_in,
                              void* d_out, int out_size, void* d_ws, size_t ws_size,
                              hipStream_t stream){
  const float* X  = (const float*)d_in[0];
  const float* Wq = (const float*)d_in[1];
  const float* bq = (const float*)d_in[2];
  const float* Wk = (const float*)d_in[3];
  const float* bk = (const float*)d_in[4];
  const float* Wv = (const float*)d_in[5];
  const float* bv = (const float*)d_in[6];
  const float* Wo = (const float*)d_in[7];
  const float* bo = (const float*)d_in[8];
  const int*   isc = (const int*)d_in[9];

  char* ws = (char*)d_ws;
  u16* Xb  = (u16*)(ws);              // 16 MiB, reused as Ob after attention
  u16* Qb  = (u16*)(ws + 16777216);
  u16* Kb  = (u16*)(ws + 33554432);
  u16* Vtb = (u16*)(ws + 50331648);
  u16* Wqb = (u16*)(ws + 67108864);
  u16* Wkb = (u16*)(ws + 75497472);
  u16* Wvb = (u16*)(ws + 83886080);
  u16* Wob = (u16*)(ws + 92274688);
  u16* Ob  = Xb;

  cast_kernel<<<2048, 256, 0, stream>>>(X,  Xb,  L * DMODEL);
  cast_kernel<<<1024, 256, 0, stream>>>(Wq, Wqb, DMODEL * DMODEL);
  cast_kernel<<<1024, 256, 0, stream>>>(Wk, Wkb, DMODEL * DMODEL);
  cast_kernel<<<1024, 256, 0, stream>>>(Wv, Wvb, DMODEL * DMODEL);
  cast_kernel<<<1024, 256, 0, stream>>>(Wo, Wob, DMODEL * DMODEL);

  dim3 gg(32, 16);
  gemm_bt<0><<<gg, 256, 0, stream>>>(Xb, Wqb, bq, Qb);
  gemm_bt<0><<<gg, 256, 0, stream>>>(Xb, Wkb, bk, Kb);
  gemm_bt<1><<<gg, 256, 0, stream>>>(Xb, Wvb, bv, Vtb);

  attn_kernel<<<512, 256, 0, stream>>>(Qb, Kb, Vtb, Ob, isc);

  gemm_bt<2><<<gg, 256, 0, stream>>>(Ob, Wob, bo, d_out);
}

// Round 3
// 396.616 us; speedup vs baseline: 2.6738x; 1.5565x over previous
//
#include <hip/hip_runtime.h>

typedef unsigned short u16;
typedef __attribute__((ext_vector_type(8))) short short8;
typedef __attribute__((ext_vector_type(4))) float f32x4;

#define L 4096
#define DMODEL 2048
#define NHEADS 16
#define DHEAD 128

__device__ __forceinline__ u16 f2bf(float f){
  union { float f; unsigned int i; } v; v.f = f;
  unsigned int u = v.i;
  u += 0x7fffu + ((u >> 16) & 1u);
  return (u16)(u >> 16);
}

__global__ void cast_kernel(const float* __restrict__ in, u16* __restrict__ out, int n){
  int stride = gridDim.x * blockDim.x * 4;
  for (int j = (blockIdx.x * blockDim.x + threadIdx.x) * 4; j < n; j += stride){
    float4 f = *reinterpret_cast<const float4*>(in + j);
    ushort4 o;
    o.x = f2bf(f.x); o.y = f2bf(f.y); o.z = f2bf(f.z); o.w = f2bf(f.w);
    *reinterpret_cast<ushort4*>(out + j) = o;
  }
}

__device__ __forceinline__ void gl_lds16(void* lds, const void* g){
  __builtin_amdgcn_global_load_lds(
      (const __attribute__((address_space(1))) unsigned int*)g,
      (__attribute__((address_space(3))) unsigned int*)lds, 16, 0, 0);
}

// C = A @ B^T (+bias). A: [4096][2048] bf16 row-major, B: [2048][2048] bf16 row-major.
// MODE 0: write bf16 out[H][L][128] at (h=col>>7, l=row, dh=col&127)   (Q, K)
// MODE 1: write bf16 out[H][128][L] at (h=col>>7, dh=col&127, l=row)   (V transposed)
// MODE 2: write f32  out[row*2048 + col]                               (final output)
template<int MODE>
__global__ __launch_bounds__(256) void gemm_bt(const u16* __restrict__ A, const u16* __restrict__ Bw,
                                               const float* __restrict__ bias, void* __restrict__ outp){
  __shared__ u16 As[128*32];
  __shared__ u16 Bs[128*32];
  const int tid = threadIdx.x;
  const int wid = tid >> 6, lane = tid & 63;
  const int wr = wid >> 1, wc = wid & 1;
  const int g = lane >> 4, r = lane & 15;

  const u16* Ag = A + ((size_t)(blockIdx.x * 128 + wid * 32 + (lane >> 2))) * DMODEL + (lane & 3) * 8;
  const u16* Bg = Bw + ((size_t)(blockIdx.y * 128 + wid * 32 + (lane >> 2))) * DMODEL + (lane & 3) * 8;
  u16* AsW = As + wid * 1024;
  u16* BsW = Bs + wid * 1024;

  f32x4 acc[4][4];
  #pragma unroll
  for (int m = 0; m < 4; ++m)
    #pragma unroll
    for (int n = 0; n < 4; ++n) acc[m][n] = (f32x4){0.f, 0.f, 0.f, 0.f};

  for (int k0 = 0; k0 < DMODEL; k0 += 32){
    __syncthreads();
    gl_lds16(AsW,       Ag + k0);
    gl_lds16(AsW + 512, Ag + k0 + 16 * DMODEL);
    gl_lds16(BsW,       Bg + k0);
    gl_lds16(BsW + 512, Bg + k0 + 16 * DMODEL);
    __syncthreads();

    short8 a[4], b[4];
    #pragma unroll
    for (int m = 0; m < 4; ++m)
      a[m] = *reinterpret_cast<const short8*>(&As[(wr * 64 + m * 16 + r) * 32 + g * 8]);
    #pragma unroll
    for (int n = 0; n < 4; ++n)
      b[n] = *reinterpret_cast<const short8*>(&Bs[(wc * 64 + n * 16 + r) * 32 + g * 8]);
    #pragma unroll
    for (int m = 0; m < 4; ++m)
      #pragma unroll
      for (int n = 0; n < 4; ++n)
        acc[m][n] = __builtin_amdgcn_mfma_f32_16x16x32_bf16(a[m], b[n], acc[m][n], 0, 0, 0);
  }

  const int ibase = blockIdx.x * 128 + wr * 64;
  const int jbase = blockIdx.y * 128 + wc * 64;
  #pragma unroll
  for (int n = 0; n < 4; ++n){
    int col = jbase + n * 16 + r;
    float bv = bias[col];
    #pragma unroll
    for (int m = 0; m < 4; ++m){
      #pragma unroll
      for (int q = 0; q < 4; ++q){
        int row = ibase + m * 16 + g * 4 + q;
        float c = acc[m][n][q] + bv;
        if (MODE == 0){
          ((u16*)outp)[(size_t)(col >> 7) * (L * DHEAD) + (size_t)row * DHEAD + (col & 127)] = f2bf(c);
        } else if (MODE == 1){
          ((u16*)outp)[(size_t)(col >> 7) * (DHEAD * L) + (size_t)(col & 127) * L + row] = f2bf(c);
        } else {
          ((float*)outp)[(size_t)row * DMODEL + col] = c;
        }
      }
    }
  }
}

// Stage one 64x128 bf16 K tile into LDS (linear dest, XOR-swizzled global source).
__device__ __forceinline__ void stage_K(u16* buf, const u16* Kh, int kv0, int wid, int lane){
  #pragma unroll
  for (int i = 0; i < 4; ++i){
    int ib = (wid * 4 + i) * 1024;
    int off = ib + lane * 16;
    int row = off >> 8;            // 256 B per kv row
    int c = off & 255;
    int sc = c ^ ((row & 7) << 4); // involutive swizzle
    gl_lds16((char*)buf + ib, (const char*)(Kh + (size_t)(kv0 + row) * DHEAD) + sc);
  }
}

// Stage one 128x64 bf16 V^T tile into LDS (rows = dh, 128 B each, swizzled).
__device__ __forceinline__ void stage_V(u16* buf, const u16* Vh, int kv0, int wid, int lane){
  #pragma unroll
  for (int i = 0; i < 4; ++i){
    int ib = (wid * 4 + i) * 1024;
    int off = ib + lane * 16;
    int row = off >> 7;            // 128 B per dh row
    int c = off & 127;
    int sc = c ^ ((row & 7) << 4);
    gl_lds16((char*)buf + ib, (const char*)(Vh + (size_t)row * L + kv0) + sc);
  }
}

// Flash attention, causal-balanced strip pairs.
// Block = 4 waves, one head, strips jA=p and jB=63-p (64 q-rows each):
// every block does exactly 65 m-tile computations -> uniform work.
// K double-buffered LDS, V^T single-buffered LDS, both XOR-swizzled.
__global__ __launch_bounds__(256, 2) void attn_kernel(const u16* __restrict__ Q, const u16* __restrict__ Km,
                                                      const u16* __restrict__ Vt, u16* __restrict__ Ob,
                                                      const int* __restrict__ is_causal_p){
  __shared__ u16 Ks[2][64 * 128];   // 32 KiB
  __shared__ u16 Vs[128 * 64];      // 16 KiB
  __shared__ u16 Ps[4][32 * 72];    // 18 KiB
  const int lane = threadIdx.x & 63, wid = threadIdx.x >> 6;
  const int g = lane >> 4, r = lane & 15;

  // XCD-chunked mapping: each XCD owns 64 consecutive lg = 2 heads.
  int lg = (blockIdx.x & 7) * 64 + (blockIdx.x >> 3);
  int head = lg >> 5;
  int p = lg & 31;
  const int causal = *is_causal_p;
  const int jA = p, jB = 63 - p;
  const int qbase[2] = {64 * jA, 64 * jB};
  const int nt = causal ? (jB + 1) : 64;

  const u16* Qh = Q  + (size_t)head * L * DHEAD;
  const u16* Kh = Km + (size_t)head * L * DHEAD;
  const u16* Vh = Vt + (size_t)head * DHEAD * L;
  u16* P = Ps[wid];

  short8 qf[2][4];
  #pragma unroll
  for (int m = 0; m < 2; ++m)
    #pragma unroll
    for (int kb = 0; kb < 4; ++kb)
      qf[m][kb] = *reinterpret_cast<const short8*>(
          &Qh[(size_t)(qbase[m] + wid * 16 + r) * DHEAD + kb * 32 + g * 8]);

  f32x4 o[2][8];
  #pragma unroll
  for (int m = 0; m < 2; ++m)
    #pragma unroll
    for (int db = 0; db < 8; ++db) o[m][db] = (f32x4){0.f, 0.f, 0.f, 0.f};
  float mrow[2][4], lrow[2][4];
  #pragma unroll
  for (int m = 0; m < 2; ++m)
    #pragma unroll
    for (int q = 0; q < 4; ++q){ mrow[m][q] = -1e30f; lrow[m][q] = 0.f; }

  const float scale = 0.08838834764831845f;  // 1/sqrt(128)

  stage_K(Ks[0], Kh, 0, wid, lane);

  for (int t = 0; t < nt; ++t){
    const int kv0 = t * 64;
    const bool more = (t + 1 < nt);
    if (more){
      stage_K(Ks[(t + 1) & 1], Kh, kv0 + 64, wid, lane);
      stage_V(Vs, Vh, kv0, wid, lane);
      asm volatile("s_waitcnt vmcnt(8)" ::: "memory");   // K[t] drained
    } else {
      stage_V(Vs, Vh, kv0, wid, lane);
      asm volatile("s_waitcnt vmcnt(4)" ::: "memory");   // K[t] drained
    }
    __builtin_amdgcn_sched_barrier(0);
    __builtin_amdgcn_s_barrier();                         // K[t] visible to all
    __builtin_amdgcn_sched_barrier(0);

    const bool actA = (!causal) || (t <= jA);             // block-uniform

    // ---- S = Q K^T ----
    const char* Kb = (const char*)Ks[t & 1];
    f32x4 s[2][4];
    #pragma unroll
    for (int m = 0; m < 2; ++m)
      #pragma unroll
      for (int cb = 0; cb < 4; ++cb) s[m][cb] = (f32x4){0.f, 0.f, 0.f, 0.f};
    #pragma unroll
    for (int cb = 0; cb < 4; ++cb){
      const int rr = cb * 16 + r;
      short8 kf[4];
      #pragma unroll
      for (int kb = 0; kb < 4; ++kb)
        kf[kb] = *reinterpret_cast<const short8*>(
            Kb + rr * 256 + ((kb * 64 + g * 16) ^ ((rr & 7) << 4)));
      if (actA){
        #pragma unroll
        for (int kb = 0; kb < 4; ++kb)
          s[0][cb] = __builtin_amdgcn_mfma_f32_16x16x32_bf16(qf[0][kb], kf[kb], s[0][cb], 0, 0, 0);
      }
      #pragma unroll
      for (int kb = 0; kb < 4; ++kb)
        s[1][cb] = __builtin_amdgcn_mfma_f32_16x16x32_bf16(qf[1][kb], kf[kb], s[1][cb], 0, 0, 0);
    }

    // ---- softmax (mask only on diagonal tiles) ----
    #pragma unroll
    for (int m = 0; m < 2; ++m){
      if (m == 0 && !actA) continue;
      const bool dg = causal && (t == (m ? jB : jA));
      float pmax[4] = {-1e30f, -1e30f, -1e30f, -1e30f};
      #pragma unroll
      for (int cb = 0; cb < 4; ++cb){
        int kvcol = kv0 + cb * 16 + r;
        #pragma unroll
        for (int q = 0; q < 4; ++q){
          float v = s[m][cb][q] * scale;
          if (dg){
            int qrow = qbase[m] + wid * 16 + g * 4 + q;
            if (kvcol > qrow) v = -1e30f;
          }
          s[m][cb][q] = v;
          pmax[q] = fmaxf(pmax[q], v);
        }
      }
      #pragma unroll
      for (int q = 0; q < 4; ++q){
        #pragma unroll
        for (int off = 1; off < 16; off <<= 1)
          pmax[q] = fmaxf(pmax[q], __shfl_xor(pmax[q], off));
      }
      float alpha[4], rsum[4];
      #pragma unroll
      for (int q = 0; q < 4; ++q){
        float mn = fmaxf(mrow[m][q], pmax[q]);
        alpha[q] = __expf(mrow[m][q] - mn);
        mrow[m][q] = mn;
        rsum[q] = 0.f;
      }
      #pragma unroll
      for (int cb = 0; cb < 4; ++cb)
        #pragma unroll
        for (int q = 0; q < 4; ++q){
          float pv = __expf(s[m][cb][q] - mrow[m][q]);
          s[m][cb][q] = pv;
          rsum[q] += pv;
        }
      #pragma unroll
      for (int q = 0; q < 4; ++q){
        #pragma unroll
        for (int off = 1; off < 16; off <<= 1)
          rsum[q] += __shfl_xor(rsum[q], off);
        lrow[m][q] = lrow[m][q] * alpha[q] + rsum[q];
      }
      #pragma unroll
      for (int db = 0; db < 8; ++db)
        #pragma unroll
        for (int q = 0; q < 4; ++q)
          o[m][db][q] *= alpha[q];
      #pragma unroll
      for (int cb = 0; cb < 4; ++cb)
        #pragma unroll
        for (int q = 0; q < 4; ++q)
          P[(m * 16 + g * 4 + q) * 72 + cb * 16 + r] = f2bf(s[m][cb][q]);
    }

    if (more) asm volatile("s_waitcnt vmcnt(4) lgkmcnt(0)" ::: "memory");  // V[t] + P done
    else      asm volatile("s_waitcnt vmcnt(0) lgkmcnt(0)" ::: "memory");
    __builtin_amdgcn_sched_barrier(0);
    __builtin_amdgcn_s_barrier();                          // V[t] visible to all
    __builtin_amdgcn_sched_barrier(0);

    // ---- O += P @ V (all operands from LDS) ----
    #pragma unroll
    for (int st = 0; st < 2; ++st){
      short8 pa[2];
      #pragma unroll
      for (int m = 0; m < 2; ++m)
        pa[m] = *reinterpret_cast<const short8*>(
            (const char*)P + (m * 16 + r) * 144 + st * 64 + g * 16);
      #pragma unroll
      for (int db = 0; db < 8; ++db){
        const int rowv = db * 16 + r;
        short8 vf = *reinterpret_cast<const short8*>(
            (const char*)Vs + rowv * 128 + ((st * 64 + g * 16) ^ ((rowv & 7) << 4)));
        if (actA)
          o[0][db] = __builtin_amdgcn_mfma_f32_16x16x32_bf16(pa[0], vf, o[0][db], 0, 0, 0);
        o[1][db] = __builtin_amdgcn_mfma_f32_16x16x32_bf16(pa[1], vf, o[1][db], 0, 0, 0);
      }
    }
    __builtin_amdgcn_sched_barrier(0);
    __builtin_amdgcn_s_barrier();                          // PV done -> Vs reusable
    __builtin_amdgcn_sched_barrier(0);
  }

  // ---- epilogue: O / l, write [L][2048] bf16 ----
  #pragma unroll
  for (int m = 0; m < 2; ++m)
    #pragma unroll
    for (int db = 0; db < 8; ++db)
      #pragma unroll
      for (int q = 0; q < 4; ++q){
        float val = o[m][db][q] / lrow[m][q];
        int qrow = qbase[m] + wid * 16 + g * 4 + q;
        Ob[(size_t)qrow * DMODEL + head * DHEAD + db * 16 + r] = f2bf(val);
      }
}

extern "C" void kernel_launch(void* const* d_in, const int* in_sizes, int n_in,
                              void* d_out, int out_size, void* d_ws, size_t ws_size,
                              hipStream_t stream){
  const float* X  = (const float*)d_in[0];
  const float* Wq = (const float*)d_in[1];
  const float* bq = (const float*)d_in[2];
  const float* Wk = (const float*)d_in[3];
  const float* bk = (const float*)d_in[4];
  const float* Wv = (const float*)d_in[5];
  const float* bv = (const float*)d_in[6];
  const float* Wo = (const float*)d_in[7];
  const float* bo = (const float*)d_in[8];
  const int*   isc = (const int*)d_in[9];

  char* ws = (char*)d_ws;
  u16* Xb  = (u16*)(ws);              // 16 MiB, reused as Ob after attention
  u16* Qb  = (u16*)(ws + 16777216);
  u16* Kb  = (u16*)(ws + 33554432);
  u16* Vtb = (u16*)(ws + 50331648);
  u16* Wqb = (u16*)(ws + 67108864);
  u16* Wkb = (u16*)(ws + 75497472);
  u16* Wvb = (u16*)(ws + 83886080);
  u16* Wob = (u16*)(ws + 92274688);
  u16* Ob  = Xb;

  cast_kernel<<<2048, 256, 0, stream>>>(X,  Xb,  L * DMODEL);
  cast_kernel<<<1024, 256, 0, stream>>>(Wq, Wqb, DMODEL * DMODEL);
  cast_kernel<<<1024, 256, 0, stream>>>(Wk, Wkb, DMODEL * DMODEL);
  cast_kernel<<<1024, 256, 0, stream>>>(Wv, Wvb, DMODEL * DMODEL);
  cast_kernel<<<1024, 256, 0, stream>>>(Wo, Wob, DMODEL * DMODEL);

  dim3 gg(32, 16);
  gemm_bt<0><<<gg, 256, 0, stream>>>(Xb, Wqb, bq, Qb);
  gemm_bt<0><<<gg, 256, 0, stream>>>(Xb, Wkb, bk, Kb);
  gemm_bt<1><<<gg, 256, 0, stream>>>(Xb, Wvb, bv, Vtb);

  attn_kernel<<<512, 256, 0, stream>>>(Qb, Kb, Vtb, Ob, isc);

  gemm_bt<2><<<gg, 256, 0, stream>>>(Ob, Wob, bo, d_out);
}